// Round 5
// baseline (94.654 us; speedup 1.0000x reference)
//
#include <hip/hip_runtime.h>

#define BB 16
#define NN 4096
#define HQ (BB * NN)        // 65536 queries per direction
#define QT (2 * HQ)         // 131072 total
#define NSLICE 8
#define DBS (NN / NSLICE)   // 512 db points per block
#define WPTS (DBS / 4)      // 128 db points per wave
#define NGRP (WPTS / 4)     // 32 groups of 4 points
#define PQ 16               // queries per lane
#define QW (64 * PQ)        // 1024 queries per block (shared by all 4 waves)
#define NQC (NN / QW)       // 4 query chunks per batch
#define RBLOCKS (QT / 4 / 256)  // 128 reduce blocks

typedef float v2f __attribute__((ext_vector_type(2)));

// Block id bits: slice[0:2], qc[3:4], b[5:8], dir[9]. 1024 blocks.
// All 4 waves share one 1024-query set (PQ=16/lane); each wave owns a
// 128-pt quarter of the block's 512-pt db slice. Per group-of-4 db points
// per query: 4 v_pk_fma_f32 + 2 v_min3_f32 = 6 inst (scalar acc keeps the
// min3 folding that round 3's disasm-era VALUBusy confirmed; v2f min may
// scalarize). LDS demand per group: 3 broadcast ds_read_b128 (~36 CU-cyc)
// vs 16 waves/CU x 192 SIMD-cyc -> VALU-bound.
__global__ __launch_bounds__(256, 4) void chamfer_partial(
    const float* __restrict__ pred, const float* __restrict__ target,
    float* __restrict__ partial, unsigned int* __restrict__ cnt) {
  const int bid = blockIdx.x;
  const int slice = bid & (NSLICE - 1);
  const int qc = (bid >> 3) & (NQC - 1);
  const int b = (bid >> 5) & (BB - 1);
  const int dir = bid >> 9;
  const int t = threadIdx.x;
  const int lane = t & 63;
  const int wid = t >> 6;

  // Zero the reduce kernel's arrival counter (ws is poisoned 0xAA every
  // call). Safe: this kernel fully retires before chamfer_reduce launches.
  if (bid == 0 && t == 0) *cnt = 0;

  // 16 KB: staging uses first 6 KB (3x512 floats); combine reuses 16 KB.
  __shared__ float smem[4096];
  float* sTX = smem;
  float* sTY = smem + DBS;
  float* sT2 = smem + 2 * DBS;

  // Stage 512 db points (opposite cloud), 2 per thread, SoA + |t|^2.
  const float2* __restrict__ dsrc = (const float2*)(dir ? pred : target);
  {
    const float4 two = ((const float4*)(dsrc + b * NN + slice * DBS))[t];
    ((float2*)sTX)[t] = {two.x, two.z};
    ((float2*)sTY)[t] = {two.y, two.w};
    ((float2*)sT2)[t] = {__builtin_fmaf(two.x, two.x, two.y * two.y),
                         __builtin_fmaf(two.z, two.z, two.w * two.w)};
  }

  // This lane's 16 queries (same set in all 4 waves; L1-hot).
  const float2* __restrict__ qsrc = (const float2*)(dir ? target : pred);
  const int qbase = b * NN + qc * QW + lane;
  v2f nx[PQ], ny[PQ];
  float acc[PQ];
#pragma unroll
  for (int k = 0; k < PQ; ++k) {
    const float2 Q = qsrc[qbase + k * 64];
    const float fx = -2.0f * Q.x, fy = -2.0f * Q.y;
    nx[k] = {fx, fx};
    ny[k] = {fy, fy};
    acc[k] = 3.4e38f;
  }
  __syncthreads();

  const float4* __restrict__ gx = (const float4*)sTX + wid * (WPTS / 4);
  const float4* __restrict__ gy = (const float4*)sTY + wid * (WPTS / 4);
  const float4* __restrict__ gs = (const float4*)sT2 + wid * (WPTS / 4);
  for (int g = 0; g < NGRP; ++g) {
    const float4 x4 = gx[g], y4 = gy[g], s4 = gs[g];
    const v2f xlo = {x4.x, x4.y}, xhi = {x4.z, x4.w};
    const v2f ylo = {y4.x, y4.y}, yhi = {y4.z, y4.w};
    const v2f slo = {s4.x, s4.y}, shi = {s4.z, s4.w};
#pragma unroll
    for (int k = 0; k < PQ; ++k) {
      v2f r0 = __builtin_elementwise_fma(ny[k], ylo, slo);
      r0 = __builtin_elementwise_fma(nx[k], xlo, r0);
      acc[k] = fminf(acc[k], fminf(r0.x, r0.y));  // v_min3_f32
      v2f r1 = __builtin_elementwise_fma(ny[k], yhi, shi);
      r1 = __builtin_elementwise_fma(nx[k], xhi, r1);
      acc[k] = fminf(acc[k], fminf(r1.x, r1.y));
    }
  }

  __syncthreads();  // all waves done reading db before smem reuse
  // Per-lane mins -> cmb[k][wid][lane] (lane-contiguous: conflict-free).
#pragma unroll
  for (int k = 0; k < PQ; ++k) smem[(k * 4 + wid) * 64 + lane] = acc[k];
  __syncthreads();

  // Thread t combines the 4 wave-mins for queries k = wid*4 .. wid*4+3.
  const int pbase = slice * QT + dir * HQ + b * NN + qc * QW + lane;
#pragma unroll
  for (int j = 0; j < 4; ++j) {
    const int k = wid * 4 + j;
    const float m = fminf(fminf(smem[(k * 4 + 0) * 64 + lane],
                                smem[(k * 4 + 1) * 64 + lane]),
                          fminf(smem[(k * 4 + 2) * 64 + lane],
                                smem[(k * 4 + 3) * 64 + lane]));
    partial[pbase + k * 64] = m;
  }
}

// Min over 8 slices (float4-vectorized), add |q|^2, block-sum; the LAST
// block to arrive (agent-scope counter) folds the 128 block-sums into the
// two outputs — no third dispatch.
__global__ __launch_bounds__(256) void chamfer_reduce(
    const float* __restrict__ pred, const float* __restrict__ target,
    const float4* __restrict__ partial4, float* __restrict__ bsum,
    unsigned int* __restrict__ cnt, float* __restrict__ out) {
  const int i = blockIdx.x * 256 + threadIdx.x;  // 0 .. QT/4, 128 blocks
  float4 m = partial4[i];
#pragma unroll
  for (int s = 1; s < NSLICE; ++s) {
    const float4 w = partial4[s * (QT / 4) + i];
    m.x = fminf(m.x, w.x);
    m.y = fminf(m.y, w.y);
    m.z = fminf(m.z, w.z);
    m.w = fminf(m.w, w.w);
  }
  const int dir = i >= (HQ / 4);  // uniform per block
  const int q0 = i * 4 - dir * HQ;
  const float2* __restrict__ qsrc = (const float2*)(dir ? target : pred);
  const float2 Q0 = qsrc[q0], Q1 = qsrc[q0 + 1];
  const float2 Q2 = qsrc[q0 + 2], Q3 = qsrc[q0 + 3];
  float v = (m.x + __builtin_fmaf(Q0.x, Q0.x, Q0.y * Q0.y)) +
            (m.y + __builtin_fmaf(Q1.x, Q1.x, Q1.y * Q1.y)) +
            (m.z + __builtin_fmaf(Q2.x, Q2.x, Q2.y * Q2.y)) +
            (m.w + __builtin_fmaf(Q3.x, Q3.x, Q3.y * Q3.y));

#pragma unroll
  for (int off = 32; off > 0; off >>= 1) v += __shfl_down(v, off, 64);
  __shared__ float red[4];
  __shared__ int is_last;
  if ((threadIdx.x & 63) == 0) red[threadIdx.x >> 6] = v;
  __syncthreads();
  if (threadIdx.x == 0) {
    const float s = (red[0] + red[1]) + (red[2] + red[3]);
    __hip_atomic_store(&bsum[blockIdx.x], s, __ATOMIC_RELEASE,
                       __HIP_MEMORY_SCOPE_AGENT);
    const unsigned int old = __hip_atomic_fetch_add(
        cnt, 1u, __ATOMIC_ACQ_REL, __HIP_MEMORY_SCOPE_AGENT);
    is_last = (old == RBLOCKS - 1);
  }
  __syncthreads();
  if (is_last) {
    const int t = threadIdx.x;
    float w = 0.0f;
    if (t < RBLOCKS)  // blocks 0..63 are dir0, 64..127 dir1
      w = __hip_atomic_load(&bsum[t], __ATOMIC_ACQUIRE,
                            __HIP_MEMORY_SCOPE_AGENT);
#pragma unroll
    for (int off = 32; off > 0; off >>= 1) w += __shfl_down(w, off, 64);
    if ((t & 63) == 0 && t < RBLOCKS) out[t >> 6] = w * (1.0f / 65536.0f);
  }
}

extern "C" void kernel_launch(void* const* d_in, const int* in_sizes, int n_in,
                              void* d_out, int out_size, void* d_ws, size_t ws_size,
                              hipStream_t stream) {
  const float* pred = (const float*)d_in[0];
  const float* target = (const float*)d_in[1];
  float* out = (float*)d_out;
  float* partial = (float*)d_ws;                              // 4 MiB
  float* bsum = (float*)((char*)d_ws + NSLICE * QT * 4);      // 512 B
  unsigned int* cnt =
      (unsigned int*)((char*)d_ws + NSLICE * QT * 4 + 512);   // 4 B

  chamfer_partial<<<2 * BB * NQC * NSLICE, 256, 0, stream>>>(pred, target,
                                                             partial, cnt);
  chamfer_reduce<<<RBLOCKS, 256, 0, stream>>>(
      pred, target, (const float4*)partial, bsum, cnt, out);
}